// Round 1
// baseline (269.920 us; speedup 1.0000x reference)
//
#include <hip/hip_runtime.h>
#include <math.h>

#define N 8192
#define N_MODES 12

// H[i][j] = 0 except:
//   H[i][i]   = 2*inv_dx2 + V[i]
//   H[i][i±1] = -inv_dx2
// V[i] = a0 + sum_k cos_c[k]*cos(2*pi*(k+1)*x_i) + sin_c[k]*sin(2*pi*(k+1)*x_i)
// x_i = i / (N-1)   (linspace(0,1,N) endpoint-inclusive)
//
// R2 strategy: ONE fused kernel writes the whole 268 MB matrix.
// Evidence from R1 counters: the memset path wrote WRITE_SIZE=1.074 GB --
// out_size is a BYTE count, so memset(out_size*4) over-filled 4x (162 us
// instead of the 41 us the 268 MB matrix needs at the 6.6 TB/s fill rate).
// Fused single pass: grid-stride over float4 slots, zero everywhere,
// patch the <=3 band entries when the 16B span crosses the diagonal.
// Only waves straddling the diagonal (~0.1% of threads) do trig.

__global__ __launch_bounds__(256) void schro_fused_fill(
    const float* __restrict__ a0,
    const float* __restrict__ cos_c,
    const float* __restrict__ sin_c,
    float* __restrict__ out)
{
    const float inv_dx2 = 67108864.0f;  // 8192^2

    const int total_q = (N / 4) * N;            // float4 slots: 16,777,216 (fits int)
    const int stride  = gridDim.x * blockDim.x; // 2048*256 = 524,288 -> 32 iters/thread

    float4* __restrict__ o4 = (float4*)out;

    for (int q = blockIdx.x * blockDim.x + threadIdx.x; q < total_q; q += stride) {
        const int e   = q << 2;        // element index (max 2^26, fits int)
        const int row = e >> 13;       // e / N
        const int c   = e & (N - 1);   // e % N  (first col of this float4)

        float4 v = make_float4(0.0f, 0.0f, 0.0f, 0.0f);

        // Band entries live at cols {row-1, row, row+1}; this float4 covers
        // cols [c, c+3]. Intersection iff row - c in [-1, 4].
        const int d = row - c;
        if (d >= -1 && d <= 4) {
            // Compute V[row] -- identical math to the absmax=0.0 R1 kernel.
            const float x = (float)row * (1.0f / (float)(N - 1));
            float V = a0[0];
            #pragma unroll
            for (int k = 0; k < N_MODES; ++k) {
                const float ph = 6.28318530717958647692f * (float)(k + 1) * x;
                V += cos_c[k] * cosf(ph) + sin_c[k] * sinf(ph);
            }
            const float diagv = 2.0f * inv_dx2 + V;

            float* pv = &v.x;
            #pragma unroll
            for (int k = 0; k < 4; ++k) {
                const int col = c + k;
                if (col == row)                          pv[k] = diagv;
                else if (col == row - 1 || col == row + 1) pv[k] = -inv_dx2;
            }
        }

        o4[q] = v;  // 16 B/lane coalesced; full-line coverage -> no RMW fetch
    }
}

extern "C" void kernel_launch(void* const* d_in, const int* in_sizes, int n_in,
                              void* d_out, int out_size, void* d_ws, size_t ws_size,
                              hipStream_t stream) {
    const float* a0    = (const float*)d_in[0];
    const float* cos_c = (const float*)d_in[1];
    const float* sin_c = (const float*)d_in[2];
    float* out = (float*)d_out;

    // Memory-bound fill: cap grid at 2048 blocks, grid-stride the rest (G11).
    schro_fused_fill<<<2048, 256, 0, stream>>>(a0, cos_c, sin_c, out);
}